// Round 1
// baseline (777.995 us; speedup 1.0000x reference)
//
#include <hip/hip_runtime.h>

// Problem: B=16, LQ=LP=2048, H=1024
//   q_lin = relu(q @ W^T + b); p_lin = relu(p @ W^T + b)
//   scores = p_lin @ q_lin^T ; att = softmax(scores, axis=2); out = att @ q_lin
// All GEMMs run in fp16 MFMA (16x16x32), f32 accumulate. Scores kept f32 for
// softmax precision; P written back as fp16 in place (row stride 4096 halfs).

#define LQN 2048
#define LPN 2048
#define HD  1024
#define NBATCH 16

typedef _Float16 half8 __attribute__((ext_vector_type(8)));
typedef _Float16 half4_t __attribute__((ext_vector_type(4)));
typedef float f32x4 __attribute__((ext_vector_type(4)));

#define GLP(src, dst) __builtin_amdgcn_global_load_lds(                          \
    (const __attribute__((address_space(1))) void*)(src),                        \
    (__attribute__((address_space(3))) void*)(dst), 16, 0, 0)

// ---------------------------------------------------------------- convert f32->f16
__global__ __launch_bounds__(256) void cvt_f32_f16(const float* __restrict__ in,
                                                   _Float16* __restrict__ out,
                                                   long n4) {
  long i0 = (long)blockIdx.x * blockDim.x + threadIdx.x;
  long stride = (long)gridDim.x * blockDim.x;
  for (long i = i0; i < n4; i += stride) {
    float4 v = ((const float4*)in)[i];
    half4_t h = {(_Float16)v.x, (_Float16)v.y, (_Float16)v.z, (_Float16)v.w};
    ((half4_t*)out)[i] = h;
  }
}

// ---------------------------------------------------------------- linear GEMM
// C[M][1024] = relu(A[M][1024] @ W[1024][1024]^T + bias), fp16 out.
// Optionally also writes transposed per-batch: CT[b][col][row&2047].
__global__ __launch_bounds__(256) void gemm_lin(const _Float16* __restrict__ A,
                                                const _Float16* __restrict__ Bm,
                                                const float* __restrict__ bias,
                                                _Float16* __restrict__ C,
                                                _Float16* __restrict__ CT,
                                                int writeT) {
  __shared__ _Float16 As[128 * 32];
  __shared__ _Float16 Bs[128 * 32];
  const int tid = threadIdx.x, lane = tid & 63, wid = tid >> 6;
  const int l16 = lane & 15, lhi = lane >> 4;
  const int wr = wid >> 1, wc = wid & 1;
  const int bm0 = blockIdx.x * 128, bn0 = blockIdx.y * 128;
  f32x4 acc[4][4] = {};

  for (int kt = 0; kt < HD; kt += 32) {
    __syncthreads();
#pragma unroll
    for (int j = 0; j < 2; ++j) {
      int rr = (wid << 5) + (j << 4) + (lane >> 2);
      int cc = kt + ((lane & 3) << 3);
      GLP(A + (size_t)(bm0 + rr) * HD + cc, &As[((wid << 5) + (j << 4)) << 5]);
      GLP(Bm + (size_t)(bn0 + rr) * HD + cc, &Bs[((wid << 5) + (j << 4)) << 5]);
    }
    __syncthreads();
    half8 af[4], bf[4];
#pragma unroll
    for (int m = 0; m < 4; ++m)
      af[m] = *(const half8*)&As[(((wr << 6) + (m << 4) + l16) << 5) + (lhi << 3)];
#pragma unroll
    for (int n = 0; n < 4; ++n)
      bf[n] = *(const half8*)&Bs[(((wc << 6) + (n << 4) + l16) << 5) + (lhi << 3)];
#pragma unroll
    for (int m = 0; m < 4; ++m)
#pragma unroll
      for (int n = 0; n < 4; ++n)
        acc[m][n] = __builtin_amdgcn_mfma_f32_16x16x32_f16(af[m], bf[n], acc[m][n], 0, 0, 0);
  }

#pragma unroll
  for (int n = 0; n < 4; ++n) {
    int col = bn0 + (wc << 6) + (n << 4) + l16;
    float bv = bias[col];
#pragma unroll
    for (int m = 0; m < 4; ++m) {
      int row0 = bm0 + (wr << 6) + (m << 4) + (lhi << 2);
      float v0 = fmaxf(acc[m][n][0] + bv, 0.f);
      float v1 = fmaxf(acc[m][n][1] + bv, 0.f);
      float v2 = fmaxf(acc[m][n][2] + bv, 0.f);
      float v3 = fmaxf(acc[m][n][3] + bv, 0.f);
      C[(size_t)(row0 + 0) * HD + col] = (_Float16)v0;
      C[(size_t)(row0 + 1) * HD + col] = (_Float16)v1;
      C[(size_t)(row0 + 2) * HD + col] = (_Float16)v2;
      C[(size_t)(row0 + 3) * HD + col] = (_Float16)v3;
      if (writeT) {
        half4_t h = {(_Float16)v0, (_Float16)v1, (_Float16)v2, (_Float16)v3};
        int bz = row0 >> 11, qi = row0 & 2047;
        *(half4_t*)&CT[(size_t)bz * ((size_t)HD * LQN) + (size_t)col * LQN + qi] = h;
      }
    }
  }
}

// ---------------------------------------------------------------- generic f32-out GEMM (bt form)
// C[M][N](f32) = A[M][K] @ B[N][K]^T, fp16 in, batched over blockIdx.z.
__global__ __launch_bounds__(256) void gemm_f32(const _Float16* __restrict__ A,
                                                const _Float16* __restrict__ Bm,
                                                float* __restrict__ C, int K,
                                                int lda, int ldb, int ldc,
                                                long sAz, long sBz, long sCz) {
  __shared__ _Float16 As[128 * 32];
  __shared__ _Float16 Bs[128 * 32];
  const _Float16* Ab = A + (size_t)blockIdx.z * sAz;
  const _Float16* Bb = Bm + (size_t)blockIdx.z * sBz;
  float* Cb = C + (size_t)blockIdx.z * sCz;
  const int tid = threadIdx.x, lane = tid & 63, wid = tid >> 6;
  const int l16 = lane & 15, lhi = lane >> 4;
  const int wr = wid >> 1, wc = wid & 1;
  const int bm0 = blockIdx.x * 128, bn0 = blockIdx.y * 128;
  f32x4 acc[4][4] = {};

  for (int kt = 0; kt < K; kt += 32) {
    __syncthreads();
#pragma unroll
    for (int j = 0; j < 2; ++j) {
      int rr = (wid << 5) + (j << 4) + (lane >> 2);
      int cc = kt + ((lane & 3) << 3);
      GLP(Ab + (size_t)(bm0 + rr) * lda + cc, &As[((wid << 5) + (j << 4)) << 5]);
      GLP(Bb + (size_t)(bn0 + rr) * ldb + cc, &Bs[((wid << 5) + (j << 4)) << 5]);
    }
    __syncthreads();
    half8 af[4], bf[4];
#pragma unroll
    for (int m = 0; m < 4; ++m)
      af[m] = *(const half8*)&As[(((wr << 6) + (m << 4) + l16) << 5) + (lhi << 3)];
#pragma unroll
    for (int n = 0; n < 4; ++n)
      bf[n] = *(const half8*)&Bs[(((wc << 6) + (n << 4) + l16) << 5) + (lhi << 3)];
#pragma unroll
    for (int m = 0; m < 4; ++m)
#pragma unroll
      for (int n = 0; n < 4; ++n)
        acc[m][n] = __builtin_amdgcn_mfma_f32_16x16x32_f16(af[m], bf[n], acc[m][n], 0, 0, 0);
  }

#pragma unroll
  for (int n = 0; n < 4; ++n) {
    int col = bn0 + (wc << 6) + (n << 4) + l16;
#pragma unroll
    for (int m = 0; m < 4; ++m) {
      int row0 = bm0 + (wr << 6) + (m << 4) + (lhi << 2);
#pragma unroll
      for (int i = 0; i < 4; ++i)
        Cb[(size_t)(row0 + i) * ldc + col] = acc[m][n][i];
    }
  }
}

// ---------------------------------------------------------------- row softmax, in-place f32->fp16
// One block per row of 2048 f32 scores; writes 2048 fp16 P over the row start.
__global__ __launch_bounds__(256) void softmax_k(float* __restrict__ buf) {
  __shared__ float red[4];
  const int t = threadIdx.x;
  float* s = buf + (size_t)blockIdx.x * 2048;
  float4 v0 = ((const float4*)s)[t * 2];
  float4 v1 = ((const float4*)s)[t * 2 + 1];
  float m = fmaxf(fmaxf(fmaxf(v0.x, v0.y), fmaxf(v0.z, v0.w)),
                  fmaxf(fmaxf(v1.x, v1.y), fmaxf(v1.z, v1.w)));
#pragma unroll
  for (int o = 32; o; o >>= 1) m = fmaxf(m, __shfl_xor(m, o));
  if ((t & 63) == 0) red[t >> 6] = m;
  __syncthreads();
  m = fmaxf(fmaxf(red[0], red[1]), fmaxf(red[2], red[3]));
  float e[8];
  e[0] = __expf(v0.x - m); e[1] = __expf(v0.y - m);
  e[2] = __expf(v0.z - m); e[3] = __expf(v0.w - m);
  e[4] = __expf(v1.x - m); e[5] = __expf(v1.y - m);
  e[6] = __expf(v1.z - m); e[7] = __expf(v1.w - m);
  float sum = ((e[0] + e[1]) + (e[2] + e[3])) + ((e[4] + e[5]) + (e[6] + e[7]));
#pragma unroll
  for (int o = 32; o; o >>= 1) sum += __shfl_xor(sum, o);
  __syncthreads();
  if ((t & 63) == 0) red[t >> 6] = sum;
  __syncthreads();
  sum = (red[0] + red[1]) + (red[2] + red[3]);
  float inv = 1.f / sum;
  half8 h;
  h[0] = (_Float16)(e[0] * inv); h[1] = (_Float16)(e[1] * inv);
  h[2] = (_Float16)(e[2] * inv); h[3] = (_Float16)(e[3] * inv);
  h[4] = (_Float16)(e[4] * inv); h[5] = (_Float16)(e[5] * inv);
  h[6] = (_Float16)(e[6] * inv); h[7] = (_Float16)(e[7] * inv);
  ((half8*)s)[t] = h;
}

// ---------------------------------------------------------------- launch
extern "C" void kernel_launch(void* const* d_in, const int* in_sizes, int n_in,
                              void* d_out, int out_size, void* d_ws, size_t ws_size,
                              hipStream_t stream) {
  const float* q = (const float*)d_in[0];
  const float* p = (const float*)d_in[1];
  const float* W = (const float*)d_in[2];
  const float* bias = (const float*)d_in[3];
  float* out = (float*)d_out;
  char* ws = (char*)d_ws;

  // ws layout (bytes):
  //   0        q_f16   64MB      (dead after linear -> reused for scores chunk)
  //   64MB     p_f16   64MB      (dead after linear -> reused for scores chunk)
  //   128MB    q_lin   64MB  fp16 [B][LQ][H]
  //   192MB    p_lin   64MB  fp16 [B][LP][H]
  //   256MB    q_linT  64MB  fp16 [B][H][LQ]
  //   320MB    W_f16    2MB
  // scores chunk (8 batches, f32 [8][2048][2048] = 128MB) reuses [0,128MB).
  _Float16* qf    = (_Float16*)(ws);
  _Float16* pf    = (_Float16*)(ws + 67108864L);
  _Float16* qlin  = (_Float16*)(ws + 134217728L);
  _Float16* plin  = (_Float16*)(ws + 201326592L);
  _Float16* qlinT = (_Float16*)(ws + 268435456L);
  _Float16* Wf    = (_Float16*)(ws + 335544320L);
  float* scores   = (float*)ws;

  const long nQ = (long)NBATCH * LQN * HD;  // 33,554,432

  cvt_f32_f16<<<2048, 256, 0, stream>>>(q, qf, nQ / 4);
  cvt_f32_f16<<<2048, 256, 0, stream>>>(p, pf, nQ / 4);
  cvt_f32_f16<<<64, 256, 0, stream>>>(W, Wf, (long)HD * HD / 4);

  dim3 glin(NBATCH * LQN / 128, HD / 128, 1);  // (256, 8)
  gemm_lin<<<glin, 256, 0, stream>>>(qf, Wf, bias, qlin, qlinT, 1);
  gemm_lin<<<glin, 256, 0, stream>>>(pf, Wf, bias, plin, (_Float16*)0, 0);

  for (int c = 0; c < 2; ++c) {
    int bz0 = c * 8;
    // scores[z][p][q] = p_lin . q_lin  (f32)
    gemm_f32<<<dim3(LPN / 128, LQN / 128, 8), 256, 0, stream>>>(
        plin + (size_t)bz0 * LPN * HD, qlin + (size_t)bz0 * LQN * HD, scores,
        /*K=*/HD, /*lda=*/HD, /*ldb=*/HD, /*ldc=*/LQN,
        (long)LPN * HD, (long)LQN * HD, (long)LPN * LQN);
    // softmax rows -> fp16 P in place (row stride 4096 halfs)
    softmax_k<<<8 * LPN, 256, 0, stream>>>(scores);
    // out[z][p][d] = P @ q_linT^T  (f32)
    gemm_f32<<<dim3(LPN / 128, HD / 128, 8), 256, 0, stream>>>(
        (const _Float16*)scores, qlinT + (size_t)bz0 * HD * LQN,
        out + (size_t)bz0 * LPN * HD,
        /*K=*/LQN, /*lda=*/2 * LQN, /*ldb=*/LQN, /*ldc=*/HD,
        (long)LPN * 2 * LQN, (long)HD * LQN, (long)LPN * HD);
  }
}

// Round 3
// 638.696 us; speedup vs baseline: 1.2181x; 1.2181x over previous
//
#include <hip/hip_runtime.h>

// B=16, LQ=LP=2048, H=1024
//   q_lin = relu(q @ W^T + b); p_lin = relu(p @ W^T + b)
//   scores = p_lin @ q_lin^T ; att = softmax(scores); out = att @ q_lin
// All GEMMs: 256x256 tile, BK=64, 8 waves, 8-phase schedule (T2 swizzle +
// counted vmcnt + setprio), fp16 MFMA 16x16x32, f32 accumulate.

#define LQN 2048
#define LPN 2048
#define HD  1024
#define NBATCH 16

typedef _Float16 half8 __attribute__((ext_vector_type(8)));
typedef _Float16 half4_t __attribute__((ext_vector_type(4)));
typedef float f32x4 __attribute__((ext_vector_type(4)));

#define GLP(src, dst) __builtin_amdgcn_global_load_lds(                          \
    (const __attribute__((address_space(1))) void*)(src),                        \
    (__attribute__((address_space(3))) void*)(dst), 16, 0, 0)

// ---------------------------------------------------------------- convert f32->f16
__global__ __launch_bounds__(256) void cvt_f32_f16(const float* __restrict__ in,
                                                   _Float16* __restrict__ out,
                                                   long n4) {
  long i0 = (long)blockIdx.x * blockDim.x + threadIdx.x;
  long stride = (long)gridDim.x * blockDim.x;
  for (long i = i0; i < n4; i += stride) {
    float4 v = ((const float4*)in)[i];
    half4_t h = {(_Float16)v.x, (_Float16)v.y, (_Float16)v.z, (_Float16)v.w};
    ((half4_t*)out)[i] = h;
  }
}

// ---------------------------------------------------------------- 8-phase 256^2 GEMM
// C[M][N] = A[M][K] @ B[N][K]^T   (bt-form, fp16 in, f32 acc)
// EPI 0: f32 C.   EPI 1: fp16 C = relu(acc+bias), plus fp16 CT transposed.
// EPI 2: fp16 C = relu(acc+bias), no CT.
// Phase schedule (per iter: tile T=2i in buf0 ph1-4, T+1 in buf1 ph5-8):
//   ph1 stage A(T+1,h1)  ph2 B(T+1,h1)  ph3 A(T+2,h0)  ph4 B(T+2,h0) +vmcnt(4)
//   ph5 stage A(T+2,h1)  ph6 B(T+2,h1)  ph7 A(T+3,h0)  ph8 B(T+3,h0) +vmcnt(4)
// Compute phase (qm,qn) reads only A-half(qm)/B-half(qn); every stage lands in a
// half whose last read was in an earlier phase (barrier-separated) -> race-free.

#define SYNC_PRE                                        \
  __builtin_amdgcn_sched_barrier(0);                    \
  __builtin_amdgcn_s_barrier();                         \
  asm volatile("s_waitcnt lgkmcnt(0)" ::: "memory");    \
  __builtin_amdgcn_sched_barrier(0);                    \
  __builtin_amdgcn_s_setprio(1);

#define SYNC_POST                                       \
  __builtin_amdgcn_s_setprio(0);                        \
  __builtin_amdgcn_sched_barrier(0);                    \
  __builtin_amdgcn_s_barrier();

#define SYNC_POST_VM                                    \
  __builtin_amdgcn_s_setprio(0);                        \
  __builtin_amdgcn_sched_barrier(0);                    \
  asm volatile("s_waitcnt vmcnt(4)" ::: "memory");      \
  __builtin_amdgcn_s_barrier();

#define LOADA(qm, buf)                                                            \
  _Pragma("unroll")                                                               \
  for (int mi = 0; mi < 4; ++mi) {                                                \
    areg[mi][0] = *(const half8*)(smA + (buf)*32768 + abase + ((qm)*4+mi)*4096);  \
    areg[mi][1] = *(const half8*)(smA + (buf)*32768 + abase + ((qm)*4+mi)*4096 + 64); \
  }

#define LOADB(qn, buf)                                                            \
  _Pragma("unroll")                                                               \
  for (int ni = 0; ni < 2; ++ni) {                                                \
    breg[ni][0] = *(const half8*)(smB + (buf)*32768 + bbase + ((qn)*2+ni)*8192);  \
    breg[ni][1] = *(const half8*)(smB + (buf)*32768 + bbase + ((qn)*2+ni)*8192 + 64); \
  }

#define STAGEA(t, h, buf) do {                                                    \
  GLP(gA + (size_t)((h)*128)*lda + (size_t)(t)*64,                                \
      smW + (buf)*32768 + (h)*16384 + wid*1024);                                  \
  GLP(gA + (size_t)((h)*128+64)*lda + (size_t)(t)*64,                             \
      smW + (buf)*32768 + (h)*16384 + 8192 + wid*1024);                           \
} while (0)

#define STAGEB(t, h, buf) do {                                                    \
  GLP(gB + (size_t)((h)*128)*ldb + (size_t)(t)*64,                                \
      smW + 65536 + (buf)*32768 + (h)*16384 + wid*1024);                          \
  GLP(gB + (size_t)((h)*128+64)*ldb + (size_t)(t)*64,                             \
      smW + 65536 + (buf)*32768 + (h)*16384 + 8192 + wid*1024);                   \
} while (0)

#define DO_MFMA(qm, qn)                                                           \
  _Pragma("unroll")                                                               \
  for (int mi = 0; mi < 4; ++mi) {                                                \
    _Pragma("unroll")                                                             \
    for (int ni = 0; ni < 2; ++ni) {                                              \
      acc[(qm)*4+mi][(qn)*2+ni] = __builtin_amdgcn_mfma_f32_16x16x32_f16(         \
          areg[mi][0], breg[ni][0], acc[(qm)*4+mi][(qn)*2+ni], 0, 0, 0);          \
      acc[(qm)*4+mi][(qn)*2+ni] = __builtin_amdgcn_mfma_f32_16x16x32_f16(         \
          areg[mi][1], breg[ni][1], acc[(qm)*4+mi][(qn)*2+ni], 0, 0, 0);          \
    }                                                                             \
  }

template <int EPI>
__global__ __launch_bounds__(512, 2) void gemm8p(
    const _Float16* __restrict__ A, const _Float16* __restrict__ B,
    const float* __restrict__ bias, void* __restrict__ Cv,
    _Float16* __restrict__ CT, int K, int lda, int ldb, int ldc,
    long sAz, long sBz, long sCz) {
  extern __shared__ __align__(16) char smem[];
  const char* smA = smem;            // A tiles: 2 x 32KB
  const char* smB = smem + 65536;    // B tiles: 2 x 32KB
  char* smW = smem;

  const int tid = threadIdx.x;
  const int lane = tid & 63, wid = tid >> 6;
  const int l16 = lane & 15, lhi = lane >> 4;
  const int wr = wid >> 2, wcn = wid & 3;

  // swizzled LDS read bases (byte): st_16x32 -> flip bit5 iff row bit2
  const int lswz = ((l16 >> 2) & 1) << 5;
  const int abase = (wr * 2048 + l16 * 128 + lhi * 16) ^ lswz;
  const int bbase = (wcn * 2048 + l16 * 128 + lhi * 16) ^ lswz;

  // inverse-swizzled staging source coords (same involution, rule #21)
  const int tl = tid ^ (((tid >> 5) & 1) << 1);
  const int srow = tl >> 3;
  const int scol = (tl & 7) * 8;

  const int bm0 = blockIdx.x * 256, bn0 = blockIdx.y * 256;
  const _Float16* gA = A + (size_t)blockIdx.z * sAz + (size_t)(bm0 + srow) * lda + scol;
  const _Float16* gB = B + (size_t)blockIdx.z * sBz + (size_t)(bn0 + srow) * ldb + scol;

  const int NT = K >> 6, NI = K >> 7;

  f32x4 acc[8][4] = {};
  half8 areg[4][2], breg[2][2];

  // prologue: tile0 (all 4 halves) + tile1 (h0 of A and B)
  STAGEA(0, 0, 0); STAGEB(0, 0, 0);
  STAGEA(0, 1, 0); STAGEB(0, 1, 0);
  STAGEA(1, 0, 1); STAGEB(1, 0, 1);
  __builtin_amdgcn_sched_barrier(0);
  asm volatile("s_waitcnt vmcnt(4)" ::: "memory");
  __builtin_amdgcn_s_barrier();

  for (int i = 0; i < NI; ++i) {
    const int t1 = 2 * i + 1;
    int t2 = 2 * i + 2; if (t2 > NT - 1) t2 = NT - 1;
    int t3 = 2 * i + 3; if (t3 > NT - 1) t3 = NT - 1;
    // ph1
    LOADA(0, 0) LOADB(0, 0) STAGEA(t1, 1, 1);
    SYNC_PRE DO_MFMA(0, 0) SYNC_POST
    // ph2
    LOADB(1, 0) STAGEB(t1, 1, 1);
    SYNC_PRE DO_MFMA(0, 1) SYNC_POST
    // ph3
    LOADA(1, 0) LOADB(0, 0) STAGEA(t2, 0, 0);
    SYNC_PRE DO_MFMA(1, 0) SYNC_POST
    // ph4
    LOADB(1, 0) STAGEB(t2, 0, 0);
    SYNC_PRE DO_MFMA(1, 1) SYNC_POST_VM
    // ph5
    LOADA(0, 1) LOADB(0, 1) STAGEA(t2, 1, 0);
    SYNC_PRE DO_MFMA(0, 0) SYNC_POST
    // ph6
    LOADB(1, 1) STAGEB(t2, 1, 0);
    SYNC_PRE DO_MFMA(0, 1) SYNC_POST
    // ph7
    LOADA(1, 1) LOADB(0, 1) STAGEA(t3, 0, 1);
    SYNC_PRE DO_MFMA(1, 0) SYNC_POST
    // ph8
    LOADB(1, 1) STAGEB(t3, 0, 1);
    SYNC_PRE DO_MFMA(1, 1) SYNC_POST_VM
  }

  // epilogue
  if constexpr (EPI == 0) {
    float* Cb = (float*)Cv + (size_t)blockIdx.z * sCz;
#pragma unroll
    for (int m = 0; m < 8; ++m) {
      int row0 = bm0 + m * 32 + wr * 16 + lhi * 4;
#pragma unroll
      for (int n = 0; n < 4; ++n) {
        int col = bn0 + n * 64 + wcn * 16 + l16;
#pragma unroll
        for (int v = 0; v < 4; ++v)
          Cb[(size_t)(row0 + v) * ldc + col] = acc[m][n][v];
      }
    }
  } else {
    _Float16* Cb = (_Float16*)Cv;
#pragma unroll
    for (int n = 0; n < 4; ++n) {
      int col = bn0 + n * 64 + wcn * 16 + l16;
      float bv = bias[col];
#pragma unroll
      for (int m = 0; m < 8; ++m) {
        int row0 = bm0 + m * 32 + wr * 16 + lhi * 4;
        float v0 = fmaxf(acc[m][n][0] + bv, 0.f);
        float v1 = fmaxf(acc[m][n][1] + bv, 0.f);
        float v2 = fmaxf(acc[m][n][2] + bv, 0.f);
        float v3 = fmaxf(acc[m][n][3] + bv, 0.f);
        Cb[(size_t)(row0 + 0) * ldc + col] = (_Float16)v0;
        Cb[(size_t)(row0 + 1) * ldc + col] = (_Float16)v1;
        Cb[(size_t)(row0 + 2) * ldc + col] = (_Float16)v2;
        Cb[(size_t)(row0 + 3) * ldc + col] = (_Float16)v3;
        if constexpr (EPI == 1) {
          half4_t h = {(_Float16)v0, (_Float16)v1, (_Float16)v2, (_Float16)v3};
          int bz = row0 >> 11, qi = row0 & 2047;
          *(half4_t*)&CT[(size_t)bz * ((size_t)HD * LQN) + (size_t)col * LQN + qi] = h;
        }
      }
    }
  }
}

// ---------------------------------------------------------------- row softmax, in-place f32->fp16
__global__ __launch_bounds__(256) void softmax_k(float* __restrict__ buf) {
  __shared__ float red[4];
  const int t = threadIdx.x;
  float* s = buf + (size_t)blockIdx.x * 2048;
  float4 v0 = ((const float4*)s)[t * 2];
  float4 v1 = ((const float4*)s)[t * 2 + 1];
  float m = fmaxf(fmaxf(fmaxf(v0.x, v0.y), fmaxf(v0.z, v0.w)),
                  fmaxf(fmaxf(v1.x, v1.y), fmaxf(v1.z, v1.w)));
#pragma unroll
  for (int o = 32; o; o >>= 1) m = fmaxf(m, __shfl_xor(m, o));
  if ((t & 63) == 0) red[t >> 6] = m;
  __syncthreads();
  m = fmaxf(fmaxf(red[0], red[1]), fmaxf(red[2], red[3]));
  float e[8];
  e[0] = __expf(v0.x - m); e[1] = __expf(v0.y - m);
  e[2] = __expf(v0.z - m); e[3] = __expf(v0.w - m);
  e[4] = __expf(v1.x - m); e[5] = __expf(v1.y - m);
  e[6] = __expf(v1.z - m); e[7] = __expf(v1.w - m);
  float sum = ((e[0] + e[1]) + (e[2] + e[3])) + ((e[4] + e[5]) + (e[6] + e[7]));
#pragma unroll
  for (int o = 32; o; o >>= 1) sum += __shfl_xor(sum, o);
  __syncthreads();
  if ((t & 63) == 0) red[t >> 6] = sum;
  __syncthreads();
  sum = (red[0] + red[1]) + (red[2] + red[3]);
  float inv = 1.f / sum;
  half8 h;
  h[0] = (_Float16)(e[0] * inv); h[1] = (_Float16)(e[1] * inv);
  h[2] = (_Float16)(e[2] * inv); h[3] = (_Float16)(e[3] * inv);
  h[4] = (_Float16)(e[4] * inv); h[5] = (_Float16)(e[5] * inv);
  h[6] = (_Float16)(e[6] * inv); h[7] = (_Float16)(e[7] * inv);
  ((half8*)s)[t] = h;
}

// ---------------------------------------------------------------- launch
extern "C" void kernel_launch(void* const* d_in, const int* in_sizes, int n_in,
                              void* d_out, int out_size, void* d_ws, size_t ws_size,
                              hipStream_t stream) {
  const float* q = (const float*)d_in[0];
  const float* p = (const float*)d_in[1];
  const float* W = (const float*)d_in[2];
  const float* bias = (const float*)d_in[3];
  float* out = (float*)d_out;
  char* ws = (char*)d_ws;

  // ws layout: [0,128MB) scratch (q_f16/p_f16, then scores chunk), then
  // q_lin, p_lin, q_linT (64MB each), W_f16 (2MB).
  _Float16* qf    = (_Float16*)(ws);
  _Float16* pf    = (_Float16*)(ws + 67108864L);
  _Float16* qlin  = (_Float16*)(ws + 134217728L);
  _Float16* plin  = (_Float16*)(ws + 201326592L);
  _Float16* qlinT = (_Float16*)(ws + 268435456L);
  _Float16* Wf    = (_Float16*)(ws + 335544320L);
  float* scores   = (float*)ws;

  const long nQ = (long)NBATCH * LQN * HD;
  const size_t SH = 131072;

  cvt_f32_f16<<<2048, 256, 0, stream>>>(q, qf, nQ / 4);
  cvt_f32_f16<<<2048, 256, 0, stream>>>(p, pf, nQ / 4);
  cvt_f32_f16<<<64, 256, 0, stream>>>(W, Wf, (long)HD * HD / 4);

  // shared linear + relu (+ transposed copy of q_lin)
  gemm8p<1><<<dim3(NBATCH * LQN / 256, HD / 256, 1), 512, SH, stream>>>(
      qf, Wf, bias, qlin, qlinT, HD, HD, HD, HD, 0, 0, 0);
  gemm8p<2><<<dim3(NBATCH * LPN / 256, HD / 256, 1), 512, SH, stream>>>(
      pf, Wf, bias, plin, (_Float16*)0, HD, HD, HD, HD, 0, 0, 0);

  for (int c = 0; c < 2; ++c) {
    int bz0 = c * 8;
    gemm8p<0><<<dim3(LPN / 256, LQN / 256, 8), 512, SH, stream>>>(
        plin + (size_t)bz0 * LPN * HD, qlin + (size_t)bz0 * LQN * HD,
        (const float*)0, scores, (_Float16*)0,
        /*K=*/HD, /*lda=*/HD, /*ldb=*/HD, /*ldc=*/LQN,
        (long)LPN * HD, (long)LQN * HD, (long)LPN * LQN);
    softmax_k<<<8 * LPN, 256, 0, stream>>>(scores);
    gemm8p<0><<<dim3(LPN / 256, HD / 256, 8), 512, SH, stream>>>(
        (const _Float16*)scores, qlinT + (size_t)bz0 * HD * LQN,
        (const float*)0, out + (size_t)bz0 * LPN * HD, (_Float16*)0,
        /*K=*/LQN, /*lda=*/2 * LQN, /*ldb=*/LQN, /*ldc=*/HD,
        (long)LPN * 2 * LQN, (long)HD * LQN, (long)LPN * HD);
  }
}

// Round 4
// 581.510 us; speedup vs baseline: 1.3379x; 1.0983x over previous
//
#include <hip/hip_runtime.h>

// B=16, LQ=LP=2048, H=1024
//   q_lin = relu(q @ W^T + b); p_lin = relu(p @ W^T + b)
//   scores = p_lin @ q_lin^T ; att = softmax(scores); out = att @ q_lin
// GEMMs: 256x256 tile, BK=64, 8 waves, 8-phase schedule, fp16 MFMA 16x16x32.
// LDS swizzle: addr ^= (row&7)<<4  (full 8-way spread; 2-reg XOR k-offsets).

#define LQN 2048
#define LPN 2048
#define HD  1024
#define NBATCH 16

typedef _Float16 half8 __attribute__((ext_vector_type(8)));
typedef _Float16 half4_t __attribute__((ext_vector_type(4)));
typedef float f32x4 __attribute__((ext_vector_type(4)));

#define GLP(src, dst) __builtin_amdgcn_global_load_lds(                          \
    (const __attribute__((address_space(1))) void*)(src),                        \
    (__attribute__((address_space(3))) void*)(dst), 16, 0, 0)

// ---------------------------------------------------------------- convert f32->f16
__global__ __launch_bounds__(256) void cvt_f32_f16(const float* __restrict__ in,
                                                   _Float16* __restrict__ out,
                                                   long n4) {
  long i0 = (long)blockIdx.x * blockDim.x + threadIdx.x;
  long stride = (long)gridDim.x * blockDim.x;
  for (long i = i0; i < n4; i += stride) {
    float4 v = ((const float4*)in)[i];
    half4_t h = {(_Float16)v.x, (_Float16)v.y, (_Float16)v.z, (_Float16)v.w};
    ((half4_t*)out)[i] = h;
  }
}

// ---------------------------------------------------------------- 8-phase 256^2 GEMM
// EPI 0: f32 C.  EPI 1: fp16 C = relu(acc+bias), + fp16 CT transposed for rows<32768.

#define SYNC_PRE                                        \
  __builtin_amdgcn_sched_barrier(0);                    \
  __builtin_amdgcn_s_barrier();                         \
  asm volatile("s_waitcnt lgkmcnt(0)" ::: "memory");    \
  __builtin_amdgcn_sched_barrier(0);                    \
  __builtin_amdgcn_s_setprio(1);

#define SYNC_POST                                       \
  __builtin_amdgcn_s_setprio(0);                        \
  __builtin_amdgcn_sched_barrier(0);                    \
  __builtin_amdgcn_s_barrier();

#define SYNC_POST_VM                                    \
  __builtin_amdgcn_s_setprio(0);                        \
  __builtin_amdgcn_sched_barrier(0);                    \
  asm volatile("s_waitcnt vmcnt(4)" ::: "memory");      \
  __builtin_amdgcn_s_barrier();

#define LOADA(qm, buf)                                                            \
  _Pragma("unroll")                                                               \
  for (int mi = 0; mi < 4; ++mi) {                                                \
    areg[mi][0] = *(const half8*)(smA + (buf)*32768 + a0 + ((qm)*4+mi)*4096);     \
    areg[mi][1] = *(const half8*)(smA + (buf)*32768 + a1 + ((qm)*4+mi)*4096);     \
  }

#define LOADB(qn, buf)                                                            \
  _Pragma("unroll")                                                               \
  for (int ni = 0; ni < 2; ++ni) {                                                \
    bregs[qn][ni][0] = *(const half8*)(smB + (buf)*32768 + b0 + ((qn)*2+ni)*8192);\
    bregs[qn][ni][1] = *(const half8*)(smB + (buf)*32768 + b1 + ((qn)*2+ni)*8192);\
  }

#define STAGEA(t, h, buf) do {                                                    \
  GLP(gA + (size_t)((h)*128)*lda + (size_t)(t)*64,                                \
      smW + (buf)*32768 + (h)*16384 + wid*1024);                                  \
  GLP(gA + (size_t)((h)*128+64)*lda + (size_t)(t)*64,                             \
      smW + (buf)*32768 + (h)*16384 + 8192 + wid*1024);                           \
} while (0)

#define STAGEB(t, h, buf) do {                                                    \
  GLP(gB + (size_t)((h)*128)*ldb + (size_t)(t)*64,                                \
      smW + 65536 + (buf)*32768 + (h)*16384 + wid*1024);                          \
  GLP(gB + (size_t)((h)*128+64)*ldb + (size_t)(t)*64,                             \
      smW + 65536 + (buf)*32768 + (h)*16384 + 8192 + wid*1024);                   \
} while (0)

#define DO_MFMA(qm, qn)                                                           \
  _Pragma("unroll")                                                               \
  for (int mi = 0; mi < 4; ++mi) {                                                \
    _Pragma("unroll")                                                             \
    for (int ni = 0; ni < 2; ++ni) {                                              \
      acc[(qm)*4+mi][(qn)*2+ni] = __builtin_amdgcn_mfma_f32_16x16x32_f16(         \
          areg[mi][0], bregs[qn][ni][0], acc[(qm)*4+mi][(qn)*2+ni], 0, 0, 0);     \
      acc[(qm)*4+mi][(qn)*2+ni] = __builtin_amdgcn_mfma_f32_16x16x32_f16(         \
          areg[mi][1], bregs[qn][ni][1], acc[(qm)*4+mi][(qn)*2+ni], 0, 0, 0);     \
    }                                                                             \
  }

template <int EPI>
__global__ __launch_bounds__(512, 2) void gemm8p(
    const _Float16* __restrict__ A, const _Float16* __restrict__ B,
    const float* __restrict__ bias, void* __restrict__ Cv,
    _Float16* __restrict__ CT, int K, int lda, int ldb, int ldc,
    long sAz, long sBz, long sCz) {
  extern __shared__ __align__(16) char smem[];
  const char* smA = smem;            // A tiles: 2 x 32KB
  const char* smB = smem + 65536;    // B tiles: 2 x 32KB
  char* smW = smem;

  const int tid = threadIdx.x;
  const int lane = tid & 63, wid = tid >> 6;
  const int l16 = lane & 15, lhi = lane >> 4;
  const int wr = wid >> 2, wcn = wid & 3;

  // full-spread swizzle: flip 16B-slot bits 4-6 by row bits 0-2
  const int mask = (l16 & 7) << 4;
  const int a0 = (wr * 2048 + l16 * 128 + lhi * 16) ^ mask;
  const int a1 = a0 ^ 64;
  const int b0 = (wcn * 2048 + l16 * 128 + lhi * 16) ^ mask;
  const int b1 = b0 ^ 64;

  // inverse-swizzled staging source coords (same involution both sides)
  const int srow = tid >> 3;
  const int scol = (((tid & 7) ^ ((tid >> 3) & 7)) << 3);

  const int bm0 = blockIdx.x * 256, bn0 = blockIdx.y * 256;
  const _Float16* gA = A + (size_t)blockIdx.z * sAz + (size_t)(bm0 + srow) * lda + scol;
  const _Float16* gB = B + (size_t)blockIdx.z * sBz + (size_t)(bn0 + srow) * ldb + scol;

  const int NT = K >> 6, NI = K >> 7;

  f32x4 acc[8][4] = {};
  half8 areg[4][2], bregs[2][2][2];

  // prologue: tile0 (4 halves) + tile1 (h0 of A and B)
  STAGEA(0, 0, 0); STAGEB(0, 0, 0);
  STAGEA(0, 1, 0); STAGEB(0, 1, 0);
  STAGEA(1, 0, 1); STAGEB(1, 0, 1);
  __builtin_amdgcn_sched_barrier(0);
  asm volatile("s_waitcnt vmcnt(4)" ::: "memory");
  __builtin_amdgcn_s_barrier();

  for (int i = 0; i < NI; ++i) {
    const int t1 = 2 * i + 1;
    int t2 = 2 * i + 2; if (t2 > NT - 1) t2 = NT - 1;
    int t3 = 2 * i + 3; if (t3 > NT - 1) t3 = NT - 1;
    // ph1
    LOADA(0, 0) LOADB(0, 0) STAGEA(t1, 1, 1);
    SYNC_PRE DO_MFMA(0, 0) SYNC_POST
    // ph2
    LOADB(1, 0) STAGEB(t1, 1, 1);
    SYNC_PRE DO_MFMA(0, 1) SYNC_POST
    // ph3  (B qn=0 still resident in bregs[0])
    LOADA(1, 0) STAGEA(t2, 0, 0);
    SYNC_PRE DO_MFMA(1, 0) SYNC_POST
    // ph4  (B qn=1 resident)
    STAGEB(t2, 0, 0);
    SYNC_PRE DO_MFMA(1, 1) SYNC_POST_VM
    // ph5
    LOADA(0, 1) LOADB(0, 1) STAGEA(t2, 1, 0);
    SYNC_PRE DO_MFMA(0, 0) SYNC_POST
    // ph6
    LOADB(1, 1) STAGEB(t2, 1, 0);
    SYNC_PRE DO_MFMA(0, 1) SYNC_POST
    // ph7
    LOADA(1, 1) STAGEA(t3, 0, 1);
    SYNC_PRE DO_MFMA(1, 0) SYNC_POST
    // ph8
    STAGEB(t3, 0, 1);
    SYNC_PRE DO_MFMA(1, 1) SYNC_POST_VM
  }

  // epilogue
  if constexpr (EPI == 0) {
    float* Cb = (float*)Cv + (size_t)blockIdx.z * sCz;
#pragma unroll
    for (int m = 0; m < 8; ++m) {
      int row0 = bm0 + m * 32 + wr * 16 + lhi * 4;
#pragma unroll
      for (int n = 0; n < 4; ++n) {
        int col = bn0 + n * 64 + wcn * 16 + l16;
#pragma unroll
        for (int v = 0; v < 4; ++v)
          Cb[(size_t)(row0 + v) * ldc + col] = acc[m][n][v];
      }
    }
  } else {
    _Float16* Cb = (_Float16*)Cv;
    const bool doCT = (bm0 < NBATCH * LQN);
#pragma unroll
    for (int n = 0; n < 4; ++n) {
      int col = bn0 + n * 64 + wcn * 16 + l16;
      float bv = bias[col];
#pragma unroll
      for (int m = 0; m < 8; ++m) {
        int row0 = bm0 + m * 32 + wr * 16 + lhi * 4;
        float v0 = fmaxf(acc[m][n][0] + bv, 0.f);
        float v1 = fmaxf(acc[m][n][1] + bv, 0.f);
        float v2 = fmaxf(acc[m][n][2] + bv, 0.f);
        float v3 = fmaxf(acc[m][n][3] + bv, 0.f);
        Cb[(size_t)(row0 + 0) * ldc + col] = (_Float16)v0;
        Cb[(size_t)(row0 + 1) * ldc + col] = (_Float16)v1;
        Cb[(size_t)(row0 + 2) * ldc + col] = (_Float16)v2;
        Cb[(size_t)(row0 + 3) * ldc + col] = (_Float16)v3;
        if (doCT) {
          half4_t h = {(_Float16)v0, (_Float16)v1, (_Float16)v2, (_Float16)v3};
          int bz = row0 >> 11, qi = row0 & 2047;
          *(half4_t*)&CT[(size_t)bz * ((size_t)HD * LQN) + (size_t)col * LQN + qi] = h;
        }
      }
    }
  }
}

// ---------------------------------------------------------------- row softmax, in-place f32->fp16
__global__ __launch_bounds__(256) void softmax_k(float* __restrict__ buf) {
  __shared__ float red[4];
  const int t = threadIdx.x;
  float* s = buf + (size_t)blockIdx.x * 2048;
  float4 v0 = ((const float4*)s)[t * 2];
  float4 v1 = ((const float4*)s)[t * 2 + 1];
  float m = fmaxf(fmaxf(fmaxf(v0.x, v0.y), fmaxf(v0.z, v0.w)),
                  fmaxf(fmaxf(v1.x, v1.y), fmaxf(v1.z, v1.w)));
#pragma unroll
  for (int o = 32; o; o >>= 1) m = fmaxf(m, __shfl_xor(m, o));
  if ((t & 63) == 0) red[t >> 6] = m;
  __syncthreads();
  m = fmaxf(fmaxf(red[0], red[1]), fmaxf(red[2], red[3]));
  float e[8];
  e[0] = __expf(v0.x - m); e[1] = __expf(v0.y - m);
  e[2] = __expf(v0.z - m); e[3] = __expf(v0.w - m);
  e[4] = __expf(v1.x - m); e[5] = __expf(v1.y - m);
  e[6] = __expf(v1.z - m); e[7] = __expf(v1.w - m);
  float sum = ((e[0] + e[1]) + (e[2] + e[3])) + ((e[4] + e[5]) + (e[6] + e[7]));
#pragma unroll
  for (int o = 32; o; o >>= 1) sum += __shfl_xor(sum, o);
  __syncthreads();
  if ((t & 63) == 0) red[t >> 6] = sum;
  __syncthreads();
  sum = (red[0] + red[1]) + (red[2] + red[3]);
  float inv = 1.f / sum;
  half8 h;
  h[0] = (_Float16)(e[0] * inv); h[1] = (_Float16)(e[1] * inv);
  h[2] = (_Float16)(e[2] * inv); h[3] = (_Float16)(e[3] * inv);
  h[4] = (_Float16)(e[4] * inv); h[5] = (_Float16)(e[5] * inv);
  h[6] = (_Float16)(e[6] * inv); h[7] = (_Float16)(e[7] * inv);
  ((half8*)s)[t] = h;
}

// ---------------------------------------------------------------- launch
extern "C" void kernel_launch(void* const* d_in, const int* in_sizes, int n_in,
                              void* d_out, int out_size, void* d_ws, size_t ws_size,
                              hipStream_t stream) {
  const float* q = (const float*)d_in[0];
  const float* p = (const float*)d_in[1];
  const float* W = (const float*)d_in[2];
  const float* bias = (const float*)d_in[3];
  float* out = (float*)d_out;
  char* ws = (char*)d_ws;

  // ws layout: [0,128MB) scratch (q_f16+p_f16 contiguous, later scores chunk),
  // then q_lin(64MB), p_lin(64MB) [contiguous M=65536], q_linT(64MB), W_f16(2MB).
  _Float16* qf    = (_Float16*)(ws);
  _Float16* pf    = (_Float16*)(ws + 67108864L);
  _Float16* qlin  = (_Float16*)(ws + 134217728L);
  _Float16* plin  = (_Float16*)(ws + 201326592L);
  _Float16* qlinT = (_Float16*)(ws + 268435456L);
  _Float16* Wf    = (_Float16*)(ws + 335544320L);
  float* scores   = (float*)ws;

  const long nQ = (long)NBATCH * LQN * HD;
  const size_t SH = 131072;

  cvt_f32_f16<<<2048, 256, 0, stream>>>(q, qf, nQ / 4);
  cvt_f32_f16<<<2048, 256, 0, stream>>>(p, pf, nQ / 4);
  cvt_f32_f16<<<64, 256, 0, stream>>>(W, Wf, (long)HD * HD / 4);

  // fused shared linear + relu over q|p (M=65536); CT only for q rows
  gemm8p<1><<<dim3(2 * NBATCH * LQN / 256, HD / 256, 1), 512, SH, stream>>>(
      qf, Wf, bias, qlin, qlinT, HD, HD, HD, HD, 0, 0, 0);

  for (int c = 0; c < 2; ++c) {
    int bz0 = c * 8;
    gemm8p<0><<<dim3(LPN / 256, LQN / 256, 8), 512, SH, stream>>>(
        plin + (size_t)bz0 * LPN * HD, qlin + (size_t)bz0 * LQN * HD,
        (const float*)0, scores, (_Float16*)0,
        /*K=*/HD, /*lda=*/HD, /*ldb=*/HD, /*ldc=*/LQN,
        (long)LPN * HD, (long)LQN * HD, (long)LPN * LQN);
    softmax_k<<<8 * LPN, 256, 0, stream>>>(scores);
    gemm8p<0><<<dim3(LPN / 256, HD / 256, 8), 512, SH, stream>>>(
        (const _Float16*)scores, qlinT + (size_t)bz0 * HD * LQN,
        (const float*)0, out + (size_t)bz0 * LPN * HD, (_Float16*)0,
        /*K=*/LQN, /*lda=*/2 * LQN, /*ldb=*/LQN, /*ldc=*/HD,
        (long)LPN * 2 * LQN, (long)HD * LQN, (long)LPN * HD);
  }
}